// Round 10
// baseline (38.125 us; speedup 1.0000x reference)
//
#include <hip/hip_runtime.h>

// Problem constants: B=16, T=64, N=128, D=512, H=512, O=256, A=18
#define DD 512
#define HH 512
#define OO 256
#define AA 18
#define ROWS 1024

typedef __attribute__((ext_vector_type(8))) short bf16x8;
typedef __attribute__((ext_vector_type(4))) float f32x4;

// f32 -> bf16 round-to-nearest-even (bit trick; inputs are finite).
__device__ __forceinline__ unsigned short f2bf(float x) {
  unsigned u = __builtin_bit_cast(unsigned, x);
  u += 0x7FFFu + ((u >> 16) & 1u);
  return (unsigned short)(u >> 16);
}

// ---------------------------------------------------------------------------
// k0: prep. blocks 0..255: obs -> obs_bf (copy-convert).
//          blocks 256..511: W1[k][n] -> W1t[n][k] bf16 (32x32 LDS tiles).
//          blocks 512..639: W2[k][n] -> W2t[n][k] bf16.
// ---------------------------------------------------------------------------
__global__ __launch_bounds__(256) void k0_prep(
    const float* __restrict__ obs, const float* __restrict__ W1,
    const float* __restrict__ W2, unsigned short* __restrict__ obs_bf,
    unsigned short* __restrict__ W1t, unsigned short* __restrict__ W2t) {
  __shared__ float tile[32][33];
  const int tid = threadIdx.x;
  const int blk = blockIdx.x;

  if (blk < 256) {
    const int base = blk * 2048 + tid * 8;
    const float4 v0 = *reinterpret_cast<const float4*>(&obs[base]);
    const float4 v1 = *reinterpret_cast<const float4*>(&obs[base + 4]);
    ushort4 a, b;
    a.x = f2bf(v0.x); a.y = f2bf(v0.y); a.z = f2bf(v0.z); a.w = f2bf(v0.w);
    b.x = f2bf(v1.x); b.y = f2bf(v1.y); b.z = f2bf(v1.z); b.w = f2bf(v1.w);
    *reinterpret_cast<ushort4*>(&obs_bf[base]) = a;
    *reinterpret_cast<ushort4*>(&obs_bf[base + 4]) = b;
  } else if (blk < 512) {
    const int t = blk - 256;                       // 16x16 tiles over [512][512]
    const int k0 = (t >> 4) * 32, n0 = (t & 15) * 32;
    const int r = tid >> 3, c4 = (tid & 7) * 4;
    const float4 v = *reinterpret_cast<const float4*>(&W1[(size_t)(k0 + r) * HH + n0 + c4]);
    tile[r][c4 + 0] = v.x; tile[r][c4 + 1] = v.y;
    tile[r][c4 + 2] = v.z; tile[r][c4 + 3] = v.w;
    __syncthreads();
    ushort4 o;
    o.x = f2bf(tile[c4 + 0][r]); o.y = f2bf(tile[c4 + 1][r]);
    o.z = f2bf(tile[c4 + 2][r]); o.w = f2bf(tile[c4 + 3][r]);
    *reinterpret_cast<ushort4*>(&W1t[(size_t)(n0 + r) * DD + k0 + c4]) = o;
  } else {
    const int t = blk - 512;                       // 16 k-tiles x 8 n-tiles
    const int k0 = (t >> 3) * 32, n0 = (t & 7) * 32;
    const int r = tid >> 3, c4 = (tid & 7) * 4;
    const float4 v = *reinterpret_cast<const float4*>(&W2[(size_t)(k0 + r) * OO + n0 + c4]);
    tile[r][c4 + 0] = v.x; tile[r][c4 + 1] = v.y;
    tile[r][c4 + 2] = v.z; tile[r][c4 + 3] = v.w;
    __syncthreads();
    ushort4 o;
    o.x = f2bf(tile[c4 + 0][r]); o.y = f2bf(tile[c4 + 1][r]);
    o.z = f2bf(tile[c4 + 2][r]); o.w = f2bf(tile[c4 + 3][r]);
    *reinterpret_cast<ushort4*>(&W2t[(size_t)(n0 + r) * HH + k0 + c4]) = o;
  }
}

// ---------------------------------------------------------------------------
// k1: U(bf16) = pathGCN1(obs @ W1). Zero-LDS MFMA GEMM: fragments loaded
// directly from global (L2-resident). 512 thr = 8 waves: row-quarter rq=w&3,
// K-half kh=w>>2 (K=256 each, 8 unrolled steps). LDS only for Gs merge +
// combine (r8-proven epilogue). Grid (16 ct, 16 rt) = 256 blocks.
// ---------------------------------------------------------------------------
__global__ __launch_bounds__(512) void k1_gemm1(
    const unsigned short* __restrict__ obs_bf,
    const unsigned short* __restrict__ W1t,
    const float* __restrict__ b1, unsigned short* __restrict__ U) {
  __shared__ float Gs[64][36];
  const int tid = threadIdx.x;
  const int lane = tid & 63;
  const int w = tid >> 6;
  const int rq = w & 3;
  const int kh = w >> 2;
  const int col0 = (blockIdx.x & 15) * 32;
  const int row0 = (blockIdx.x >> 4) * 64;
  const int lr = lane & 15;
  const int lk = (lane >> 4) * 8;

  for (int i = tid; i < 64 * 36; i += 512) ((float*)Gs)[i] = 0.f;

  const unsigned short* Ap = &obs_bf[(size_t)(row0 + rq * 16 + lr) * DD + kh * 256 + lk];
  const unsigned short* Bp0 = &W1t[(size_t)(col0 + lr) * DD + kh * 256 + lk];
  const unsigned short* Bp1 = Bp0 + (size_t)16 * DD;

  f32x4 acc0 = {0.f, 0.f, 0.f, 0.f}, acc1 = {0.f, 0.f, 0.f, 0.f};
#pragma unroll
  for (int s = 0; s < 8; ++s) {
    const bf16x8 af = *reinterpret_cast<const bf16x8*>(Ap + s * 32);
    const bf16x8 b0 = *reinterpret_cast<const bf16x8*>(Bp0 + s * 32);
    const bf16x8 b1f = *reinterpret_cast<const bf16x8*>(Bp1 + s * 32);
    acc0 = __builtin_amdgcn_mfma_f32_16x16x32_bf16(af, b0, acc0, 0, 0, 0);
    acc1 = __builtin_amdgcn_mfma_f32_16x16x32_bf16(af, b1f, acc1, 0, 0, 0);
  }
  __syncthreads();   // zero-init visible to all before atomics

  // Merge K-halves. C/D layout: col = lane&15, row = (lane>>4)*4 + reg.
  const int crow = rq * 16 + (lane >> 4) * 4;
#pragma unroll
  for (int i = 0; i < 4; ++i) atomicAdd(&Gs[crow + i][lr], acc0[i]);
#pragma unroll
  for (int i = 0; i < 4; ++i) atomicAdd(&Gs[crow + i][16 + lr], acc1[i]);
  __syncthreads();

  // Path-GCN layer-1 combine -> U (bf16). t == local row (tile == one batch).
  {
    const int rr = tid >> 3;
    const int c4 = (tid & 7) * 4;
    const int t = rr;
    const float is6 = 0.4082482904638630f;  // 1/sqrt(6)
    float c0, c1, c2, d1, d2, al, be;
    if (t <= 1) {
      c0 = 0.f; c1 = 0.f; c2 = 1.f; d1 = 0.f; d2 = 0.f; al = 1.f; be = 0.f;
    } else if (t == 2) {
      c0 = 0.f; c1 = 0.5f; c2 = 0.5f; d1 = 0.5f; d2 = 0.5f; al = 0.5f; be = 0.5f;
    } else {
      c0 = (t == 3) ? is6 : (1.f / 3.f);
      c1 = 1.f / 3.f; c2 = is6;
      d1 = is6; d2 = 0.5f;
      al = is6; be = 0.5f;
    }
    const int rm1 = (t >= 1) ? rr - 1 : rr;
    const int rm2 = (t >= 2) ? rr - 2 : rr;
    ushort4 uo;
    unsigned short* up = (unsigned short*)&uo;
#pragma unroll
    for (int j = 0; j < 4; ++j) {
      const int c = c4 + j;
      const float gc = Gs[rr][c], gb = Gs[rm1][c], ga = Gs[rm2][c];
      const float bb = b1[col0 + c];
      const float h1a = fmaxf(c0 * ga + c1 * gb + c2 * gc + bb, 0.f);
      const float h1b = fmaxf(d1 * gb + d2 * gc + bb, 0.f);
      up[j] = f2bf(al * h1a + be * h1b);
    }
    *reinterpret_cast<ushort4*>(&U[(size_t)(row0 + rr) * HH + col0 + c4]) = uo;
  }
}

// ---------------------------------------------------------------------------
// k2: Tg = relu(U @ W2 + b2), f32 out. Zero-LDS MFMA, full K=512.
// 512 thr = 8 waves: row-half rh=w&1, K-group kq=w>>1 (K=128, 4 steps).
// Grid (8 ct, 32 rt) = 256 blocks.
// ---------------------------------------------------------------------------
__global__ __launch_bounds__(512) void k2_gemm2(
    const unsigned short* __restrict__ U,
    const unsigned short* __restrict__ W2t,
    const float* __restrict__ b2, float* __restrict__ Tg) {
  __shared__ float Gs[32][36];
  const int tid = threadIdx.x;
  const int lane = tid & 63;
  const int w = tid >> 6;
  const int rh = w & 1;
  const int kq = w >> 1;
  const int col0 = (blockIdx.x & 7) * 32;
  const int row0 = (blockIdx.x >> 3) * 32;
  const int lr = lane & 15;
  const int lk = (lane >> 4) * 8;

  for (int i = tid; i < 32 * 36; i += 512) ((float*)Gs)[i] = 0.f;

  const unsigned short* Ap = &U[(size_t)(row0 + rh * 16 + lr) * HH + kq * 128 + lk];
  const unsigned short* Bp0 = &W2t[(size_t)(col0 + lr) * HH + kq * 128 + lk];
  const unsigned short* Bp1 = Bp0 + (size_t)16 * HH;

  f32x4 acc0 = {0.f, 0.f, 0.f, 0.f}, acc1 = {0.f, 0.f, 0.f, 0.f};
#pragma unroll
  for (int s = 0; s < 4; ++s) {
    const bf16x8 af = *reinterpret_cast<const bf16x8*>(Ap + s * 32);
    const bf16x8 b0 = *reinterpret_cast<const bf16x8*>(Bp0 + s * 32);
    const bf16x8 b1f = *reinterpret_cast<const bf16x8*>(Bp1 + s * 32);
    acc0 = __builtin_amdgcn_mfma_f32_16x16x32_bf16(af, b0, acc0, 0, 0, 0);
    acc1 = __builtin_amdgcn_mfma_f32_16x16x32_bf16(af, b1f, acc1, 0, 0, 0);
  }
  __syncthreads();

  const int crow = rh * 16 + (lane >> 4) * 4;
#pragma unroll
  for (int i = 0; i < 4; ++i) atomicAdd(&Gs[crow + i][lr], acc0[i]);
#pragma unroll
  for (int i = 0; i < 4; ++i) atomicAdd(&Gs[crow + i][16 + lr], acc1[i]);
  __syncthreads();

  for (int i = tid; i < 32 * 32; i += 512) {
    const int r = i >> 5, c = i & 31;
    Tg[(size_t)(row0 + r) * OO + col0 + c] =
        fmaxf(Gs[r][c] + b2[col0 + c], 0.f);
  }
}

// ---------------------------------------------------------------------------
// k3: out = Tg @ Wl + bl. 8 rows/block, 128 blocks (r6-proven shape).
// ---------------------------------------------------------------------------
__global__ __launch_bounds__(256) void k3_head(
    const float* __restrict__ Tg, const float* __restrict__ Wl,
    const float* __restrict__ bl, float* __restrict__ out) {
  __shared__ float sW[OO * AA];
  __shared__ float sT[8][OO + 8];

  const int tid = threadIdx.x;
  for (int i = tid; i < OO * AA; i += 256) sW[i] = Wl[i];
  const int r0 = blockIdx.x * 8;
  for (int i = tid; i < 8 * OO; i += 256) {
    const int m = i >> 8, k = i & 255;
    sT[m][k] = Tg[(size_t)(r0 + m) * OO + k];
  }
  __syncthreads();

  if (tid < 8 * AA) {
    const int m = tid / AA;
    const int o = tid - m * AA;
    float s = bl[o];
#pragma unroll 8
    for (int k = 0; k < OO; ++k) s = fmaf(sT[m][k], sW[k * AA + o], s);
    out[(size_t)(r0 + m) * AA + o] = s;
  }
}

extern "C" void kernel_launch(void* const* d_in, const int* in_sizes, int n_in,
                              void* d_out, int out_size, void* d_ws, size_t ws_size,
                              hipStream_t stream) {
  const float* obs = (const float*)d_in[0];   // [1024, 512]
  const float* W1 = (const float*)d_in[4];    // [512, 512]
  const float* b1 = (const float*)d_in[5];    // [512]
  const float* W2 = (const float*)d_in[6];    // [512, 256]
  const float* b2 = (const float*)d_in[7];    // [256]
  const float* Wl = (const float*)d_in[8];    // [256, 18]
  const float* bl = (const float*)d_in[9];    // [18]
  float* out = (float*)d_out;                 // [1024, 18]

  unsigned short* obs_bf = (unsigned short*)d_ws;               // 1 MiB
  unsigned short* W1t = obs_bf + (size_t)ROWS * DD;             // 0.5 MiB
  unsigned short* W2t = W1t + (size_t)HH * DD;                  // 0.25 MiB
  unsigned short* U = W2t + (size_t)OO * HH;                    // 1 MiB
  float* Tg = (float*)(U + (size_t)ROWS * HH);                  // 1 MiB f32

  // 1) prep: bf16 convert + weight transposes. 640 blocks.
  k0_prep<<<640, 256, 0, stream>>>(obs, W1, W2, obs_bf, W1t, W2t);

  // 2) GEMM1 + path-GCN combine. 256 blocks x 512 thr, zero-LDS MFMA.
  k1_gemm1<<<256, 512, 0, stream>>>(obs_bf, W1t, b1, U);

  // 3) GEMM2 + bias + relu. 256 blocks x 512 thr, zero-LDS MFMA.
  k2_gemm2<<<256, 512, 0, stream>>>(U, W2t, b2, Tg);

  // 4) head. 128 blocks.
  k3_head<<<ROWS / 8, 256, 0, stream>>>(Tg, Wl, bl, out);
}

// Round 11
// 28.147 us; speedup vs baseline: 1.3545x; 1.3545x over previous
//
#include <hip/hip_runtime.h>

// Problem constants: B=16, T=64, N=128, D=512, H=512, O=256, A=18
#define DD 512
#define HH 512
#define OO 256
#define AA 18
#define ROWS 1024

typedef __attribute__((ext_vector_type(8))) short bf16x8;
typedef __attribute__((ext_vector_type(4))) float f32x4;

// f32 -> bf16 round-to-nearest-even (bit trick; inputs are finite).
__device__ __forceinline__ unsigned short f2bf(float x) {
  unsigned u = __builtin_bit_cast(unsigned, x);
  u += 0x7FFFu + ((u >> 16) & 1u);
  return (unsigned short)(u >> 16);
}

// ---------------------------------------------------------------------------
// k1: U(bf16) = pathGCN1(obs @ W1). Tile 64x32 (64 rows == one batch, so
// t == local row). 512 thr = 2 K-groups x 4 waves; each group K=256 as
// 4 chunks of BK=64 (halved barrier count vs r8). MFMA 16x16x32_bf16.
// A LDS [64][72] row-major bf16, B LDS [32][72] transposed bf16.
// Grid: 16 col-tiles x 16 row-tiles = 256 blocks.
// ---------------------------------------------------------------------------
__global__ __launch_bounds__(512) void k1_mfma_combine(
    const float* __restrict__ obs, const float* __restrict__ W1,
    const float* __restrict__ b1, unsigned short* __restrict__ U) {
  __shared__ unsigned short As[2][64][72];
  __shared__ unsigned short Bt[2][32][72];
  __shared__ float Gs[64][36];

  const int tid = threadIdx.x;
  const int g = tid >> 8;              // K-group
  const int gt = tid & 255;
  const int lane = tid & 63;
  const int wid = (tid >> 6) & 3;      // wave within group
  const int col0 = (blockIdx.x & 15) * 32;
  const int row0 = (blockIdx.x >> 4) * 64;
  const int k0 = g * 256;

  const int sar = gt >> 2, sak = (gt & 3) * 16;   // A staging: row, k-ofs
  const int sbc = gt & 31, sbk = (gt >> 5) * 8;   // B staging: col, k-ofs
  const int lr = lane & 15, lk = (lane >> 4) * 8; // fragment indices

  for (int i = tid; i < 64 * 36; i += 512) ((float*)Gs)[i] = 0.f;

  float4 pa0, pa1, pa2, pa3;
  float pb0, pb1, pb2, pb3, pb4, pb5, pb6, pb7;
  f32x4 acc0 = {0.f, 0.f, 0.f, 0.f}, acc1 = {0.f, 0.f, 0.f, 0.f};

#define LOADG(kb)                                                              \
  {                                                                            \
    const float* Ap = &obs[(size_t)(row0 + sar) * DD + (kb) + sak];            \
    pa0 = *reinterpret_cast<const float4*>(Ap);                                \
    pa1 = *reinterpret_cast<const float4*>(Ap + 4);                            \
    pa2 = *reinterpret_cast<const float4*>(Ap + 8);                            \
    pa3 = *reinterpret_cast<const float4*>(Ap + 12);                           \
    const float* Bp = &W1[(size_t)((kb) + sbk) * HH + col0 + sbc];             \
    pb0 = Bp[0]; pb1 = Bp[HH]; pb2 = Bp[2 * HH]; pb3 = Bp[3 * HH];             \
    pb4 = Bp[4 * HH]; pb5 = Bp[5 * HH]; pb6 = Bp[6 * HH]; pb7 = Bp[7 * HH];    \
  }
#define STOLDS()                                                               \
  {                                                                            \
    bf16x8 v0, v1;                                                             \
    v0[0] = (short)f2bf(pa0.x); v0[1] = (short)f2bf(pa0.y);                    \
    v0[2] = (short)f2bf(pa0.z); v0[3] = (short)f2bf(pa0.w);                    \
    v0[4] = (short)f2bf(pa1.x); v0[5] = (short)f2bf(pa1.y);                    \
    v0[6] = (short)f2bf(pa1.z); v0[7] = (short)f2bf(pa1.w);                    \
    v1[0] = (short)f2bf(pa2.x); v1[1] = (short)f2bf(pa2.y);                    \
    v1[2] = (short)f2bf(pa2.z); v1[3] = (short)f2bf(pa2.w);                    \
    v1[4] = (short)f2bf(pa3.x); v1[5] = (short)f2bf(pa3.y);                    \
    v1[6] = (short)f2bf(pa3.z); v1[7] = (short)f2bf(pa3.w);                    \
    *reinterpret_cast<bf16x8*>(&As[g][sar][sak]) = v0;                         \
    *reinterpret_cast<bf16x8*>(&As[g][sar][sak + 8]) = v1;                     \
    bf16x8 w;                                                                  \
    w[0] = (short)f2bf(pb0); w[1] = (short)f2bf(pb1);                          \
    w[2] = (short)f2bf(pb2); w[3] = (short)f2bf(pb3);                          \
    w[4] = (short)f2bf(pb4); w[5] = (short)f2bf(pb5);                          \
    w[6] = (short)f2bf(pb6); w[7] = (short)f2bf(pb7);                          \
    *reinterpret_cast<bf16x8*>(&Bt[g][sbc][sbk]) = w;                          \
  }
#define COMPUTE()                                                              \
  {                                                                            \
    _Pragma("unroll") for (int ks = 0; ks < 2; ++ks) {                         \
      const bf16x8 af =                                                        \
          *reinterpret_cast<const bf16x8*>(&As[g][wid * 16 + lr][ks * 32 + lk]); \
      const bf16x8 bf0 =                                                       \
          *reinterpret_cast<const bf16x8*>(&Bt[g][lr][ks * 32 + lk]);          \
      const bf16x8 bf1 =                                                       \
          *reinterpret_cast<const bf16x8*>(&Bt[g][16 + lr][ks * 32 + lk]);     \
      acc0 = __builtin_amdgcn_mfma_f32_16x16x32_bf16(af, bf0, acc0, 0, 0, 0);  \
      acc1 = __builtin_amdgcn_mfma_f32_16x16x32_bf16(af, bf1, acc1, 0, 0, 0);  \
    }                                                                          \
  }

  LOADG(k0);
  STOLDS();
  __syncthreads();
  for (int tt = 1; tt < 4; ++tt) {
    LOADG(k0 + tt * 64);
    COMPUTE();
    __syncthreads();
    STOLDS();
    __syncthreads();
  }
  COMPUTE();
  __syncthreads();
#undef LOADG
#undef STOLDS
#undef COMPUTE

  // Merge both K-groups' accumulators into Gs (f32).
  // C/D layout: col = lane&15, row = (lane>>4)*4 + reg.
  {
    const int crow = wid * 16 + (lane >> 4) * 4;
#pragma unroll
    for (int i = 0; i < 4; ++i) atomicAdd(&Gs[crow + i][lr], acc0[i]);
#pragma unroll
    for (int i = 0; i < 4; ++i) atomicAdd(&Gs[crow + i][16 + lr], acc1[i]);
  }
  __syncthreads();

  // Path-GCN layer-1 combine -> U (bf16). t == local row (tile == one batch).
  {
    const int rr = tid >> 3;
    const int c4 = (tid & 7) * 4;
    const int t = rr;
    const float is6 = 0.4082482904638630f;  // 1/sqrt(6)
    float c0, c1, c2, d1, d2, al, be;
    if (t <= 1) {
      c0 = 0.f; c1 = 0.f; c2 = 1.f; d1 = 0.f; d2 = 0.f; al = 1.f; be = 0.f;
    } else if (t == 2) {
      c0 = 0.f; c1 = 0.5f; c2 = 0.5f; d1 = 0.5f; d2 = 0.5f; al = 0.5f; be = 0.5f;
    } else {
      c0 = (t == 3) ? is6 : (1.f / 3.f);
      c1 = 1.f / 3.f; c2 = is6;
      d1 = is6; d2 = 0.5f;
      al = is6; be = 0.5f;
    }
    const int rm1 = (t >= 1) ? rr - 1 : rr;
    const int rm2 = (t >= 2) ? rr - 2 : rr;
    ushort4 uo;
    unsigned short* up = (unsigned short*)&uo;
#pragma unroll
    for (int j = 0; j < 4; ++j) {
      const int c = c4 + j;
      const float gc = Gs[rr][c], gb = Gs[rm1][c], ga = Gs[rm2][c];
      const float bb = b1[col0 + c];
      const float h1a = fmaxf(c0 * ga + c1 * gb + c2 * gc + bb, 0.f);
      const float h1b = fmaxf(d1 * gb + d2 * gc + bb, 0.f);
      up[j] = f2bf(al * h1a + be * h1b);
    }
    *reinterpret_cast<ushort4*>(&U[(size_t)(row0 + rr) * HH + col0 + c4]) = uo;
  }
}

// ---------------------------------------------------------------------------
// k2: fused GEMM2 + head. Per block (ct 0..7, rt 0..31): tile 32 rows x
// 32 n-cols of tgt = relu(U @ W2 + b2), full K=512 as 4 chunks of BK=128;
// then head partial: tgt_tile @ Wl[col-slice] -> atomicAdd into out
// (out pre-zeroed; bl added by ct==0 only). 256 thr = 4 waves.
// ---------------------------------------------------------------------------
__global__ __launch_bounds__(256) void k2_fused_head(
    const unsigned short* __restrict__ U, const float* __restrict__ W2,
    const float* __restrict__ b2, const float* __restrict__ Wl,
    const float* __restrict__ bl, float* __restrict__ out) {
  __shared__ unsigned short As2[32][136];
  __shared__ unsigned short Bt2[32][136];
  __shared__ float tg[32][36];
  __shared__ float sWl[32][18];

  const int tid = threadIdx.x;
  const int lane = tid & 63;
  const int w = tid >> 6;
  const int rt2 = w & 1, nt2 = w >> 1;
  const int ct = blockIdx.x & 7;
  const int col0 = ct * 32;
  const int r0 = (blockIdx.x >> 3) * 32;
  const int lr = lane & 15, lk = (lane >> 4) * 8;

  const int sar = tid >> 3, sak = (tid & 7) * 16;   // A: row, k-ofs (2 x bf16x8)
  const int sbn = tid & 31, sbk = (tid >> 5) * 16;  // B: col, k-ofs (16 scalars)

  bf16x8 pa0, pa1;
  float pb[16];
  f32x4 acc = {0.f, 0.f, 0.f, 0.f};

#define LOADG(kb)                                                              \
  {                                                                            \
    const unsigned short* Ap = &U[(size_t)(r0 + sar) * HH + (kb) + sak];       \
    pa0 = *reinterpret_cast<const bf16x8*>(Ap);                                \
    pa1 = *reinterpret_cast<const bf16x8*>(Ap + 8);                            \
    const float* Bp = &W2[(size_t)((kb) + sbk) * OO + col0 + sbn];             \
    _Pragma("unroll") for (int kk = 0; kk < 16; ++kk)                          \
        pb[kk] = Bp[(size_t)kk * OO];                                          \
  }
#define STOLDS()                                                               \
  {                                                                            \
    *reinterpret_cast<bf16x8*>(&As2[sar][sak]) = pa0;                          \
    *reinterpret_cast<bf16x8*>(&As2[sar][sak + 8]) = pa1;                      \
    bf16x8 w0, w1;                                                             \
    _Pragma("unroll") for (int kk = 0; kk < 8; ++kk)                           \
        w0[kk] = (short)f2bf(pb[kk]);                                          \
    _Pragma("unroll") for (int kk = 0; kk < 8; ++kk)                           \
        w1[kk] = (short)f2bf(pb[8 + kk]);                                      \
    *reinterpret_cast<bf16x8*>(&Bt2[sbn][sbk]) = w0;                           \
    *reinterpret_cast<bf16x8*>(&Bt2[sbn][sbk + 8]) = w1;                       \
  }
#define COMPUTE()                                                              \
  {                                                                            \
    _Pragma("unroll") for (int ks = 0; ks < 4; ++ks) {                         \
      const bf16x8 af =                                                        \
          *reinterpret_cast<const bf16x8*>(&As2[rt2 * 16 + lr][ks * 32 + lk]); \
      const bf16x8 bf =                                                        \
          *reinterpret_cast<const bf16x8*>(&Bt2[nt2 * 16 + lr][ks * 32 + lk]); \
      acc = __builtin_amdgcn_mfma_f32_16x16x32_bf16(af, bf, acc, 0, 0, 0);     \
    }                                                                          \
  }

  LOADG(0);
  STOLDS();
  __syncthreads();
  for (int tt = 1; tt < 4; ++tt) {
    LOADG(tt * 128);
    COMPUTE();
    __syncthreads();
    STOLDS();
    __syncthreads();
  }
  COMPUTE();
  __syncthreads();
#undef LOADG
#undef STOLDS
#undef COMPUTE

  // Write tgt tile (rows by rt2, cols by nt2 -> disjoint, plain stores).
  {
    const int crow = rt2 * 16 + (lane >> 4) * 4;
#pragma unroll
    for (int i = 0; i < 4; ++i) tg[crow + i][nt2 * 16 + lr] = acc[i];
  }
  // Stage Wl col-slice: [32 n][18 o].
  for (int i = tid; i < 32 * AA; i += 256) {
    const int n = i / AA, o = i - n * AA;
    sWl[n][o] = Wl[(size_t)(col0 + n) * AA + o];
  }
  __syncthreads();

  // b2 + relu in place.
  for (int i = tid; i < 32 * 32; i += 256) {
    const int r = i >> 5, c = i & 31;
    tg[r][c] = fmaxf(tg[r][c] + b2[col0 + c], 0.f);
  }
  __syncthreads();

  // Head partial: out[r0+r][o] += sum_n tg[r][n] * sWl[n][o]  (+bl if ct==0).
  for (int p = tid; p < 32 * AA; p += 256) {
    const int r = p / AA, o = p - r * AA;
    float s = (ct == 0) ? bl[o] : 0.f;
#pragma unroll 8
    for (int n = 0; n < 32; ++n) s = fmaf(tg[r][n], sWl[n][o], s);
    atomicAdd(&out[(size_t)(r0 + r) * AA + o], s);
  }
}

extern "C" void kernel_launch(void* const* d_in, const int* in_sizes, int n_in,
                              void* d_out, int out_size, void* d_ws, size_t ws_size,
                              hipStream_t stream) {
  const float* obs = (const float*)d_in[0];   // [1024, 512]
  const float* W1 = (const float*)d_in[4];    // [512, 512]
  const float* b1 = (const float*)d_in[5];    // [512]
  const float* W2 = (const float*)d_in[6];    // [512, 256]
  const float* b2 = (const float*)d_in[7];    // [256]
  const float* Wl = (const float*)d_in[8];    // [256, 18]
  const float* bl = (const float*)d_in[9];    // [18]
  float* out = (float*)d_out;                 // [1024, 18]

  unsigned short* U = (unsigned short*)d_ws;  // 1024x512 bf16 = 1 MiB

  // Zero out (head accumulates atomically into it).
  hipMemsetAsync(out, 0, (size_t)out_size * sizeof(float), stream);

  // 1) U = pathGCN1(obs @ W1), MFMA, BK=64 (4 chunks/K-group). 256 blocks.
  k1_mfma_combine<<<256, 512, 0, stream>>>(obs, W1, b1, U);

  // 2) GEMM2 (BK=128, 4 chunks) + fused head with atomic out. 256 blocks.
  k2_fused_head<<<256, 256, 0, stream>>>(U, W2, b2, Wl, bl, out);
}

// Round 12
// 23.592 us; speedup vs baseline: 1.6160x; 1.1931x over previous
//
#include <hip/hip_runtime.h>

// Problem constants: B=16, T=64, N=128, D=512, H=512, O=256, A=18
#define DD 512
#define HH 512
#define OO 256
#define AA 18
#define ROWS 1024

typedef __attribute__((ext_vector_type(8))) short bf16x8;
typedef __attribute__((ext_vector_type(4))) float f32x4;

// f32 -> bf16 round-to-nearest-even (bit trick; inputs are finite).
__device__ __forceinline__ unsigned short f2bf(float x) {
  unsigned u = __builtin_bit_cast(unsigned, x);
  u += 0x7FFFu + ((u >> 16) & 1u);
  return (unsigned short)(u >> 16);
}

// ---------------------------------------------------------------------------
// k1: U(bf16) = pathGCN1(obs @ W1)  [r11-proven core], plus two prologue
// chores that remove a dispatch and lighten k2:
//   - zero its disjoint 72-float slice of out (replaces memset dispatch)
//   - convert one W2 column-row: W2t[n=blk][k] bf16 (contiguous per block)
// Tile 64x32 (64 rows == one batch -> t == local row). 512 thr = 2 K-groups
// x 4 waves; each group K=256 as 4 chunks of BK=64. MFMA 16x16x32_bf16.
// Grid: 16 col-tiles x 16 row-tiles = 256 blocks.
// ---------------------------------------------------------------------------
__global__ __launch_bounds__(512) void k1_mfma_combine(
    const float* __restrict__ obs, const float* __restrict__ W1,
    const float* __restrict__ b1, const float* __restrict__ W2,
    unsigned short* __restrict__ U, unsigned short* __restrict__ W2t,
    float* __restrict__ out) {
  __shared__ unsigned short As[2][64][72];
  __shared__ unsigned short Bt[2][32][72];
  __shared__ float Gs[64][36];

  const int tid = threadIdx.x;
  const int blk = blockIdx.x;
  const int g = tid >> 8;              // K-group
  const int gt = tid & 255;
  const int lane = tid & 63;
  const int wid = (tid >> 6) & 3;      // wave within group
  const int col0 = (blk & 15) * 32;
  const int row0 = (blk >> 4) * 64;
  const int k0 = g * 256;

  // Prologue chore 1: zero out slice (256 blocks x 72 = 18432 = 1024*18).
  if (tid < 72) out[blk * 72 + tid] = 0.f;
  // Prologue chore 2: W2t[n=blk][k=tid] = bf16(W2[k][n]). One load+store/thr.
  W2t[(size_t)blk * HH + tid] = f2bf(W2[(size_t)tid * OO + blk]);

  const int sar = gt >> 2, sak = (gt & 3) * 16;   // A staging: row, k-ofs
  const int sbc = gt & 31, sbk = (gt >> 5) * 8;   // B staging: col, k-ofs
  const int lr = lane & 15, lk = (lane >> 4) * 8; // fragment indices

  for (int i = tid; i < 64 * 36; i += 512) ((float*)Gs)[i] = 0.f;

  float4 pa0, pa1, pa2, pa3;
  float pb0, pb1, pb2, pb3, pb4, pb5, pb6, pb7;
  f32x4 acc0 = {0.f, 0.f, 0.f, 0.f}, acc1 = {0.f, 0.f, 0.f, 0.f};

#define LOADG(kb)                                                              \
  {                                                                            \
    const float* Ap = &obs[(size_t)(row0 + sar) * DD + (kb) + sak];            \
    pa0 = *reinterpret_cast<const float4*>(Ap);                                \
    pa1 = *reinterpret_cast<const float4*>(Ap + 4);                            \
    pa2 = *reinterpret_cast<const float4*>(Ap + 8);                            \
    pa3 = *reinterpret_cast<const float4*>(Ap + 12);                           \
    const float* Bp = &W1[(size_t)((kb) + sbk) * HH + col0 + sbc];             \
    pb0 = Bp[0]; pb1 = Bp[HH]; pb2 = Bp[2 * HH]; pb3 = Bp[3 * HH];             \
    pb4 = Bp[4 * HH]; pb5 = Bp[5 * HH]; pb6 = Bp[6 * HH]; pb7 = Bp[7 * HH];    \
  }
#define STOLDS()                                                               \
  {                                                                            \
    bf16x8 v0, v1;                                                             \
    v0[0] = (short)f2bf(pa0.x); v0[1] = (short)f2bf(pa0.y);                    \
    v0[2] = (short)f2bf(pa0.z); v0[3] = (short)f2bf(pa0.w);                    \
    v0[4] = (short)f2bf(pa1.x); v0[5] = (short)f2bf(pa1.y);                    \
    v0[6] = (short)f2bf(pa1.z); v0[7] = (short)f2bf(pa1.w);                    \
    v1[0] = (short)f2bf(pa2.x); v1[1] = (short)f2bf(pa2.y);                    \
    v1[2] = (short)f2bf(pa2.z); v1[3] = (short)f2bf(pa2.w);                    \
    v1[4] = (short)f2bf(pa3.x); v1[5] = (short)f2bf(pa3.y);                    \
    v1[6] = (short)f2bf(pa3.z); v1[7] = (short)f2bf(pa3.w);                    \
    *reinterpret_cast<bf16x8*>(&As[g][sar][sak]) = v0;                         \
    *reinterpret_cast<bf16x8*>(&As[g][sar][sak + 8]) = v1;                     \
    bf16x8 w;                                                                  \
    w[0] = (short)f2bf(pb0); w[1] = (short)f2bf(pb1);                          \
    w[2] = (short)f2bf(pb2); w[3] = (short)f2bf(pb3);                          \
    w[4] = (short)f2bf(pb4); w[5] = (short)f2bf(pb5);                          \
    w[6] = (short)f2bf(pb6); w[7] = (short)f2bf(pb7);                          \
    *reinterpret_cast<bf16x8*>(&Bt[g][sbc][sbk]) = w;                          \
  }
#define COMPUTE()                                                              \
  {                                                                            \
    _Pragma("unroll") for (int ks = 0; ks < 2; ++ks) {                         \
      const bf16x8 af =                                                        \
          *reinterpret_cast<const bf16x8*>(&As[g][wid * 16 + lr][ks * 32 + lk]); \
      const bf16x8 bf0 =                                                       \
          *reinterpret_cast<const bf16x8*>(&Bt[g][lr][ks * 32 + lk]);          \
      const bf16x8 bf1 =                                                       \
          *reinterpret_cast<const bf16x8*>(&Bt[g][16 + lr][ks * 32 + lk]);     \
      acc0 = __builtin_amdgcn_mfma_f32_16x16x32_bf16(af, bf0, acc0, 0, 0, 0);  \
      acc1 = __builtin_amdgcn_mfma_f32_16x16x32_bf16(af, bf1, acc1, 0, 0, 0);  \
    }                                                                          \
  }

  LOADG(k0);
  STOLDS();
  __syncthreads();
  for (int tt = 1; tt < 4; ++tt) {
    LOADG(k0 + tt * 64);
    COMPUTE();
    __syncthreads();
    STOLDS();
    __syncthreads();
  }
  COMPUTE();
  __syncthreads();
#undef LOADG
#undef STOLDS
#undef COMPUTE

  // Merge both K-groups' accumulators into Gs (f32).
  // C/D layout: col = lane&15, row = (lane>>4)*4 + reg.
  {
    const int crow = wid * 16 + (lane >> 4) * 4;
#pragma unroll
    for (int i = 0; i < 4; ++i) atomicAdd(&Gs[crow + i][lr], acc0[i]);
#pragma unroll
    for (int i = 0; i < 4; ++i) atomicAdd(&Gs[crow + i][16 + lr], acc1[i]);
  }
  __syncthreads();

  // Path-GCN layer-1 combine -> U (bf16). t == local row (tile == one batch).
  {
    const int rr = tid >> 3;
    const int c4 = (tid & 7) * 4;
    const int t = rr;
    const float is6 = 0.4082482904638630f;  // 1/sqrt(6)
    float c0, c1, c2, d1, d2, al, be;
    if (t <= 1) {
      c0 = 0.f; c1 = 0.f; c2 = 1.f; d1 = 0.f; d2 = 0.f; al = 1.f; be = 0.f;
    } else if (t == 2) {
      c0 = 0.f; c1 = 0.5f; c2 = 0.5f; d1 = 0.5f; d2 = 0.5f; al = 0.5f; be = 0.5f;
    } else {
      c0 = (t == 3) ? is6 : (1.f / 3.f);
      c1 = 1.f / 3.f; c2 = is6;
      d1 = is6; d2 = 0.5f;
      al = is6; be = 0.5f;
    }
    const int rm1 = (t >= 1) ? rr - 1 : rr;
    const int rm2 = (t >= 2) ? rr - 2 : rr;
    ushort4 uo;
    unsigned short* up = (unsigned short*)&uo;
#pragma unroll
    for (int j = 0; j < 4; ++j) {
      const int c = c4 + j;
      const float gc = Gs[rr][c], gb = Gs[rm1][c], ga = Gs[rm2][c];
      const float bb = b1[col0 + c];
      const float h1a = fmaxf(c0 * ga + c1 * gb + c2 * gc + bb, 0.f);
      const float h1b = fmaxf(d1 * gb + d2 * gc + bb, 0.f);
      up[j] = f2bf(al * h1a + be * h1b);
    }
    *reinterpret_cast<ushort4*>(&U[(size_t)(row0 + rr) * HH + col0 + c4]) = uo;
  }
}

// ---------------------------------------------------------------------------
// k2: fused GEMM2 + head [r11-proven structure], B now pre-converted bf16
// W2t[n][k] -> staging is two coalesced bf16x8 loads (no f2bf, no strided
// f32). Per block (ct 0..7, rt 0..31): tgt tile 32 rows x 32 cols =
// relu(U @ W2 + b2), K=512 as 4 chunks of BK=128; head partial atomicAdd
// into out (zeroed by k1; bl added by ct==0). 256 thr = 4 waves.
// ---------------------------------------------------------------------------
__global__ __launch_bounds__(256) void k2_fused_head(
    const unsigned short* __restrict__ U, const unsigned short* __restrict__ W2t,
    const float* __restrict__ b2, const float* __restrict__ Wl,
    const float* __restrict__ bl, float* __restrict__ out) {
  __shared__ unsigned short As2[32][136];
  __shared__ unsigned short Bt2[32][136];
  __shared__ float tg[32][36];
  __shared__ float sWl[32][18];

  const int tid = threadIdx.x;
  const int lane = tid & 63;
  const int w = tid >> 6;
  const int rt2 = w & 1, nt2 = w >> 1;
  const int ct = blockIdx.x & 7;
  const int col0 = ct * 32;
  const int r0 = (blockIdx.x >> 3) * 32;
  const int lr = lane & 15, lk = (lane >> 4) * 8;

  const int sar = tid >> 3, sak = (tid & 7) * 16;   // A: row, k-ofs
  const int sbn = tid & 31, sbk = (tid >> 5) * 16;  // B: n-row, k-ofs

  bf16x8 pa0, pa1, pb0, pb1;
  f32x4 acc = {0.f, 0.f, 0.f, 0.f};

#define LOADG(kb)                                                              \
  {                                                                            \
    const unsigned short* Ap = &U[(size_t)(r0 + sar) * HH + (kb) + sak];       \
    pa0 = *reinterpret_cast<const bf16x8*>(Ap);                                \
    pa1 = *reinterpret_cast<const bf16x8*>(Ap + 8);                            \
    const unsigned short* Bp = &W2t[(size_t)(col0 + sbn) * HH + (kb) + sbk];   \
    pb0 = *reinterpret_cast<const bf16x8*>(Bp);                                \
    pb1 = *reinterpret_cast<const bf16x8*>(Bp + 8);                            \
  }
#define STOLDS()                                                               \
  {                                                                            \
    *reinterpret_cast<bf16x8*>(&As2[sar][sak]) = pa0;                          \
    *reinterpret_cast<bf16x8*>(&As2[sar][sak + 8]) = pa1;                      \
    *reinterpret_cast<bf16x8*>(&Bt2[sbn][sbk]) = pb0;                          \
    *reinterpret_cast<bf16x8*>(&Bt2[sbn][sbk + 8]) = pb1;                      \
  }
#define COMPUTE()                                                              \
  {                                                                            \
    _Pragma("unroll") for (int ks = 0; ks < 4; ++ks) {                         \
      const bf16x8 af =                                                        \
          *reinterpret_cast<const bf16x8*>(&As2[rt2 * 16 + lr][ks * 32 + lk]); \
      const bf16x8 bf =                                                        \
          *reinterpret_cast<const bf16x8*>(&Bt2[nt2 * 16 + lr][ks * 32 + lk]); \
      acc = __builtin_amdgcn_mfma_f32_16x16x32_bf16(af, bf, acc, 0, 0, 0);     \
    }                                                                          \
  }

  LOADG(0);
  STOLDS();
  __syncthreads();
  for (int tt = 1; tt < 4; ++tt) {
    LOADG(tt * 128);
    COMPUTE();
    __syncthreads();
    STOLDS();
    __syncthreads();
  }
  COMPUTE();
  __syncthreads();
#undef LOADG
#undef STOLDS
#undef COMPUTE

  // Write tgt tile (rows by rt2, cols by nt2 -> disjoint, plain stores).
  {
    const int crow = rt2 * 16 + (lane >> 4) * 4;
#pragma unroll
    for (int i = 0; i < 4; ++i) tg[crow + i][nt2 * 16 + lr] = acc[i];
  }
  // Stage Wl col-slice: [32 n][18 o].
  for (int i = tid; i < 32 * AA; i += 256) {
    const int n = i / AA, o = i - n * AA;
    sWl[n][o] = Wl[(size_t)(col0 + n) * AA + o];
  }
  __syncthreads();

  // b2 + relu in place.
  for (int i = tid; i < 32 * 32; i += 256) {
    const int r = i >> 5, c = i & 31;
    tg[r][c] = fmaxf(tg[r][c] + b2[col0 + c], 0.f);
  }
  __syncthreads();

  // Head partial: out[r0+r][o] += sum_n tg[r][n] * sWl[n][o]  (+bl if ct==0).
  for (int p = tid; p < 32 * AA; p += 256) {
    const int r = p / AA, o = p - r * AA;
    float s = (ct == 0) ? bl[o] : 0.f;
#pragma unroll 8
    for (int n = 0; n < 32; ++n) s = fmaf(tg[r][n], sWl[n][o], s);
    atomicAdd(&out[(size_t)(r0 + r) * AA + o], s);
  }
}

extern "C" void kernel_launch(void* const* d_in, const int* in_sizes, int n_in,
                              void* d_out, int out_size, void* d_ws, size_t ws_size,
                              hipStream_t stream) {
  const float* obs = (const float*)d_in[0];   // [1024, 512]
  const float* W1 = (const float*)d_in[4];    // [512, 512]
  const float* b1 = (const float*)d_in[5];    // [512]
  const float* W2 = (const float*)d_in[6];    // [512, 256]
  const float* b2 = (const float*)d_in[7];    // [256]
  const float* Wl = (const float*)d_in[8];    // [256, 18]
  const float* bl = (const float*)d_in[9];    // [18]
  float* out = (float*)d_out;                 // [1024, 18]

  unsigned short* U = (unsigned short*)d_ws;          // 1024x512 bf16 = 1 MiB
  unsigned short* W2t = U + (size_t)ROWS * HH;        // 256x512 bf16 = 256 KiB

  // 1) U = pathGCN1(obs @ W1) + {zero out, W2->W2t bf16}. 256 blocks.
  k1_mfma_combine<<<256, 512, 0, stream>>>(obs, W1, b1, W2, U, W2t, out);

  // 2) GEMM2 (bf16 B, BK=128, 4 chunks) + fused head. 256 blocks.
  k2_fused_head<<<256, 256, 0, stream>>>(U, W2t, b2, Wl, bl, out);
}